// Round 13
// baseline (446.702 us; speedup 1.0000x reference)
//
#include <hip/hip_runtime.h>
#include <hip/hip_bf16.h>
#include <math.h>

#define B_   8
#define L_   1024
#define DM_  256
#define NL_  4
#define ED_  512
#define NS_  16
#define DC_  4
#define RK_  16
#define CD_  64
#define Q_   2

#define SEG_  32    // segments along L
#define SLEN_ 32    // L_/SEG_

typedef __hip_bfloat16 bf16_t;
typedef __attribute__((ext_vector_type(8))) short short8;
typedef __attribute__((ext_vector_type(4))) float floatx4;

__device__ __forceinline__ float geluf(float x) {
    return 0.5f * x * (1.0f + erff(x * 0.70710678118654752f));
}
__device__ __forceinline__ float siluf(float x) {
    return x / (1.0f + __expf(-x));
}
// fast softplus: dlt is stored as bf16 (8-bit mantissa) -> ~1e-6 abs error invisible
__device__ __forceinline__ float softplus_fast(float x) {
    return (x > 20.0f) ? x : __logf(1.0f + __expf(x));
}
__device__ __forceinline__ float b2f(bf16_t v) { return __bfloat162float(v); }
__device__ __forceinline__ short f2bfbits(float v) {
    return __builtin_bit_cast(short, __float2bfloat16(v));
}
// packed {xs(hi16) | dlt(lo16)} helpers — bit-identical to separate bf16 loads
__device__ __forceinline__ float pk_lo(unsigned int u) {
    return __uint_as_float(u << 16);
}
__device__ __forceinline__ float pk_hi(unsigned int u) {
    return __uint_as_float(u & 0xFFFF0000u);
}

// ---------------- one-shot batched weight transpose + bf16 convert,
// plus the conditioning/adaLN prep folded in as blockIdx.z == 12.
__global__ void k_transpose_all(const float* __restrict__ in_w,
                                const float* __restrict__ xp_w,
                                const float* __restrict__ out_w,
                                bf16_t* __restrict__ in_wT,
                                bf16_t* __restrict__ xp_wT,
                                bf16_t* __restrict__ out_wT,
                                const float* __restrict__ T,
                                const float* __restrict__ tw1,
                                const float* __restrict__ tb1,
                                const float* __restrict__ tw2,
                                const float* __restrict__ tb2,
                                const float* __restrict__ apw,
                                const float* __restrict__ apb,
                                float* __restrict__ ss) {
    int z = blockIdx.z;
    if (z == 12) {
        // ---- prep: cond vector + per-layer adaLN params (32 real blocks)
        __shared__ float h[CD_], cnd[CD_];
        int b = blockIdx.x, layer = blockIdx.y;
        if (b >= B_ || layer >= NL_) return;
        int tid = threadIdx.x;
        if (tid < CD_) h[tid] = geluf(T[b] * tw1[tid] + tb1[tid]);
        __syncthreads();
        if (tid < CD_) {
            float acc = tb2[tid];
            #pragma unroll
            for (int c = 0; c < CD_; c++) acc += h[c] * tw2[c * CD_ + tid];
            cnd[tid] = acc;
        }
        __syncthreads();
        const float* w = apw + (size_t)layer * CD_ * 2 * DM_;
        for (int j = tid; j < 2 * DM_; j += 256) {
            float acc = apb[layer * 2 * DM_ + j];
            #pragma unroll
            for (int c = 0; c < CD_; c++) acc += cnd[c] * w[c * 2 * DM_ + j];
            ss[((size_t)layer * B_ + b) * 2 * DM_ + j] = acc;
        }
        return;
    }
    __shared__ float t[32][33];
    int which = z >> 2, layer = z & 3;
    const float* src; bf16_t* dst; int R, C;
    if (which == 0)      { R = DM_; C = 2 * ED_; src = in_w;  dst = in_wT;  }
    else if (which == 1) { R = ED_; C = 48;      src = xp_w;  dst = xp_wT;  }
    else                 { R = ED_; C = DM_;     src = out_w; dst = out_wT; }
    src += (size_t)layer * R * C;
    dst += (size_t)layer * R * C;
    int c0 = blockIdx.x * 32, r0 = blockIdx.y * 32;
    if (c0 >= C || r0 >= R) return;
    int tx = threadIdx.x & 31, ty = threadIdx.x >> 5;   // 32 x 8
    #pragma unroll
    for (int i = 0; i < 32; i += 8) {
        int r = r0 + ty + i, c = c0 + tx;
        t[ty + i][tx] = (r < R && c < C) ? src[(size_t)r * C + c] : 0.f;
    }
    __syncthreads();
    #pragma unroll
    for (int i = 0; i < 32; i += 8) {
        int c = c0 + ty + i, r = r0 + tx;
        if (c < C && r < R) dst[(size_t)c * R + r] = __float2bfloat16(t[tx][ty + i]);
    }
}

// ---------------- FUSED embed + layer-0 LN/adaLN modulation.
// Wave per row, 4 rows/block. Writes x (residual base) AND xn (layer-0 input).
__global__ __launch_bounds__(256) void k_embed_ln_mod(
        const int* __restrict__ tokens,
        const float* __restrict__ tok_embed,
        const float* __restrict__ pos_embed,
        const float* __restrict__ ag, const float* __restrict__ ab,
        const float* __restrict__ ss,
        float* __restrict__ x, bf16_t* __restrict__ xn) {
    int lane = threadIdx.x & 63, w = threadIdx.x >> 6;
    int row = blockIdx.x * 4 + w;
    int b = row >> 10, l = row & (L_ - 1);
    int tok = (l > 0) ? tokens[b * L_ + l - 1] : 0;
    float v[4];
    #pragma unroll
    for (int k = 0; k < 4; k++) {
        int c = lane + 64 * k;
        float val = pos_embed[l * DM_ + c];
        if (l > 0) val += tok_embed[tok * DM_ + c];
        v[k] = val;
        x[(size_t)row * DM_ + c] = val;
    }
    float s = (v[0] + v[1]) + (v[2] + v[3]);
    float q = (v[0] * v[0] + v[1] * v[1]) + (v[2] * v[2] + v[3] * v[3]);
    #pragma unroll
    for (int off = 32; off > 0; off >>= 1) {
        s += __shfl_xor(s, off, 64);
        q += __shfl_xor(q, off, 64);
    }
    float mean = s * (1.0f / DM_);
    float var = q * (1.0f / DM_) - mean * mean;
    float rstd = rsqrtf(var + 1e-5f);
    const float* ssl = ss + (size_t)b * 2 * DM_;   // layer 0
    #pragma unroll
    for (int k = 0; k < 4; k++) {
        int c = lane + 64 * k;
        float ln = (v[k] - mean) * rstd * ag[c] + ab[c];
        float val = (1.0f + ssl[c]) * ln + ssl[DM_ + c];
        xn[(size_t)row * DM_ + c] = __float2bfloat16(val);
    }
}

// ---------------- LN + adaLN modulation -> xn (bf16). Wave per row, 4 rows/block.
__global__ __launch_bounds__(256) void k_ln_mod(
        const float* __restrict__ x,
        const float* __restrict__ ag, const float* __restrict__ ab,
        const float* __restrict__ ss,
        bf16_t* __restrict__ xn, int layer) {
    int lane = threadIdx.x & 63, w = threadIdx.x >> 6;
    int row = blockIdx.x * 4 + w;
    int b = row >> 10;            // / L_
    const float* xr = x + (size_t)row * DM_;
    float v[4];
    #pragma unroll
    for (int k = 0; k < 4; k++) v[k] = xr[lane + 64 * k];
    float s = (v[0] + v[1]) + (v[2] + v[3]);
    float q = (v[0] * v[0] + v[1] * v[1]) + (v[2] * v[2] + v[3] * v[3]);
    #pragma unroll
    for (int off = 32; off > 0; off >>= 1) {
        s += __shfl_xor(s, off, 64);
        q += __shfl_xor(q, off, 64);
    }
    float mean = s * (1.0f / DM_);
    float var = q * (1.0f / DM_) - mean * mean;
    float rstd = rsqrtf(var + 1e-5f);
    const float* ssl = ss + ((size_t)layer * B_ + b) * 2 * DM_;
    #pragma unroll
    for (int k = 0; k < 4; k++) {
        int c = lane + 64 * k;
        float ln = (v[k] - mean) * rstd * ag[layer * DM_ + c] + ab[layer * DM_ + c];
        float val = (1.0f + ssl[c]) * ln + ssl[DM_ + c];
        xn[(size_t)row * DM_ + c] = __float2bfloat16(val);
    }
}

// ---------------- in-projection GEMM: xz = xn @ in_wT^T, silu on z half.
// BM=128 x BN=128, 512 blocks (2 blocks/CU), 16 MFMA/wave/K-step.
__global__ __launch_bounds__(256) void k_gemm_in(
        const bf16_t* __restrict__ A, const bf16_t* __restrict__ Bt,
        bf16_t* __restrict__ xz) {
    constexpr int BM = 128, BN = 128, K = 256, N = 2 * ED_;
    constexpr int TM = 4, TN = 4;
    __shared__ __align__(16) unsigned short sA[BM * 40];
    __shared__ __align__(16) unsigned short sB[BN * 40];

    const int tid = threadIdx.x;
    const int wave = tid >> 6, lane = tid & 63;
    const int lrow = lane & 15, lq = lane >> 4;
    const int nrt = (B_ * L_) / BM;     // 64
    const int bi = blockIdx.x;
    const int row0 = (bi % nrt) * BM, col0 = (bi / nrt) * BN;
    const int wm0 = (wave >> 1) * 64;
    const int wn0 = (wave & 1) * 64;

    floatx4 acc[TM][TN];
    #pragma unroll
    for (int i = 0; i < TM; i++)
        #pragma unroll
        for (int j = 0; j < TN; j++) acc[i][j] = (floatx4)0.0f;

    short8 ra[2], rb[2];
    const int NKB = K / 32;   // 8

    #pragma unroll
    for (int i = 0; i < 2; i++) {
        int v = tid + i * 256;          // 0..511, m in 0..127
        int m = v >> 2, ko = (v & 3) * 8;
        ra[i] = *(const short8*)(A + (size_t)(row0 + m) * K + ko);
        rb[i] = *(const short8*)(Bt + (size_t)(col0 + m) * K + ko);
    }

    for (int kb = 0; kb < NKB; kb++) {
        __syncthreads();
        #pragma unroll
        for (int i = 0; i < 2; i++) {
            int v = tid + i * 256;
            int m = v >> 2, ko = (v & 3) * 8;
            *(short8*)&sA[m * 40 + ko] = ra[i];
            *(short8*)&sB[m * 40 + ko] = rb[i];
        }
        __syncthreads();
        if (kb + 1 < NKB) {
            int k0 = (kb + 1) * 32;
            #pragma unroll
            for (int i = 0; i < 2; i++) {
                int v = tid + i * 256;
                int m = v >> 2, ko = (v & 3) * 8;
                ra[i] = *(const short8*)(A + (size_t)(row0 + m) * K + k0 + ko);
                rb[i] = *(const short8*)(Bt + (size_t)(col0 + m) * K + k0 + ko);
            }
        }
        short8 af[TM], bfr[TN];
        #pragma unroll
        for (int i = 0; i < TM; i++)
            af[i] = *(const short8*)&sA[(wm0 + i * 16 + lrow) * 40 + lq * 8];
        #pragma unroll
        for (int j = 0; j < TN; j++)
            bfr[j] = *(const short8*)&sB[(wn0 + j * 16 + lrow) * 40 + lq * 8];
        #pragma unroll
        for (int i = 0; i < TM; i++)
            #pragma unroll
            for (int j = 0; j < TN; j++)
                acc[i][j] = __builtin_amdgcn_mfma_f32_16x16x32_bf16(af[i], bfr[j], acc[i][j], 0, 0, 0);
    }

    #pragma unroll
    for (int i = 0; i < TM; i++) {
        int gr0 = row0 + wm0 + i * 16 + lq * 4;
        #pragma unroll
        for (int j = 0; j < TN; j++) {
            int gc = col0 + wn0 + j * 16 + lrow;
            #pragma unroll
            for (int r = 0; r < 4; r++) {
                float val = acc[i][j][r];
                if (gc >= ED_) val = siluf(val);
                xz[(size_t)(gr0 + r) * N + gc] = __float2bfloat16(val);
            }
        }
    }
}

// ---------------- FUSED: causal depthwise conv(DC=4)+SiLU -> LDS A-tile ->
// xp-projection GEMM (B from L2, barrier-free K-loop) -> packed {xs|dlt}.
// BM=16 -> 512 blocks (2 blocks/CU).
__global__ __launch_bounds__(256) void k_conv_xp_dlt(
        const bf16_t* __restrict__ xz,
        const float* __restrict__ conv_w, const float* __restrict__ conv_b,
        const bf16_t* __restrict__ Bt,      // xp_wT for this layer: [48][512]
        unsigned int* __restrict__ dxp,     // packed {xs(hi)|dlt(lo)} per (row,e)
        float* __restrict__ xd,
        const float* __restrict__ dt_w, const float* __restrict__ dt_b,
        int layer) {
    constexpr int K = ED_;   // 512
    constexpr int BM = 16;
    __shared__ __align__(16) unsigned short sA[BM][520];
    __shared__ __align__(16) float s_rk[BM][20];

    const int tid = threadIdx.x;
    const int wave = tid >> 6, lane = tid & 63;
    const int lrow = lane & 15, lq = lane >> 4;
    const int row0 = blockIdx.x * BM;
    const int b = row0 >> 10;           // / L_
    const int l0 = row0 & (L_ - 1);

    // ---- conv + silu: thread owns columns e0, e0+1 for rows row0..row0+15
    {
        const int e0 = tid * 2;
        float4 w0 = *(const float4*)(conv_w + ((size_t)layer * ED_ + e0) * DC_);
        float4 w1 = *(const float4*)(conv_w + ((size_t)layer * ED_ + e0 + 1) * DC_);
        float bias0 = conv_b[layer * ED_ + e0];
        float bias1 = conv_b[layer * ED_ + e0 + 1];
        const float wa0[4] = {w0.x, w0.y, w0.z, w0.w};
        const float wa1[4] = {w1.x, w1.y, w1.z, w1.w};
        float v0[BM + 3], v1[BM + 3];
        #pragma unroll
        for (int k = 0; k < BM + 3; k++) {
            int ll = l0 - 3 + k;
            if (ll >= 0) {
                __hip_bfloat162 v = *(const __hip_bfloat162*)(
                    xz + ((size_t)(b * L_ + ll)) * (2 * ED_) + e0);
                v0[k] = b2f(v.x); v1[k] = b2f(v.y);
            } else { v0[k] = 0.f; v1[k] = 0.f; }
        }
        #pragma unroll
        for (int j = 0; j < BM; j++) {
            float a0 = bias0, a1 = bias1;
            #pragma unroll
            for (int k = 0; k < DC_; k++) {
                a0 = fmaf(v0[j + k], wa0[k], a0);
                a1 = fmaf(v1[j + k], wa1[k], a1);
            }
            __hip_bfloat162 o;
            o.x = __float2bfloat16(siluf(a0));
            o.y = __float2bfloat16(siluf(a1));
            *(__hip_bfloat162*)&sA[j][e0] = o;     // xs bits live in LDS only
        }
    }
    __syncthreads();

    // ---- GEMM from LDS A + global(L2) B, no barriers in K-loop
    const int nrow = (wave < 3) ? (wave * 16 + lrow) : lrow;  // wave3 clamped
    const bf16_t* bptr = Bt + (size_t)nrow * K + lq * 8;
    floatx4 acc = (floatx4)0.0f;
    #pragma unroll
    for (int kb = 0; kb < K / 32; kb++) {
        short8 af = *(const short8*)&sA[lrow][kb * 32 + lq * 8];
        short8 bf = *(const short8*)(bptr + kb * 32);
        acc = __builtin_amdgcn_mfma_f32_16x16x32_bf16(af, bf, acc, 0, 0, 0);
    }

    if (wave == 1 || wave == 2) {
        int gc = wave * 16 + lrow;
        #pragma unroll
        for (int r = 0; r < 4; r++) {
            int gr = row0 + lq * 4 + r;
            xd[(size_t)gr * 48 + gc] = acc[r];
        }
    }
    if (wave == 0) {
        #pragma unroll
        for (int r = 0; r < 4; r++)
            s_rk[lq * 4 + r][lrow] = acc[r];
    }
    __syncthreads();

    // ---- dlt = softplus(rk @ dt_w + dt_b); pack with xs bits -> dxp
    const int e = 2 * tid;
    float2 wv[16];
    #pragma unroll
    for (int r = 0; r < RK_; r++)
        wv[r] = *(const float2*)(dt_w + ((size_t)layer * RK_ + r) * ED_ + e);
    float2 bb = *(const float2*)(dt_b + (size_t)layer * ED_ + e);
    #pragma unroll 4
    for (int row = 0; row < BM; row++) {
        float rk[16];
        #pragma unroll
        for (int q = 0; q < 4; q++)
            *(float4*)&rk[q * 4] = *(const float4*)&s_rk[row][q * 4];
        float a0 = bb.x, a1 = bb.y;
        #pragma unroll
        for (int r = 0; r < RK_; r++) {
            a0 = fmaf(rk[r], wv[r].x, a0);
            a1 = fmaf(rk[r], wv[r].y, a1);
        }
        unsigned int d0 = (unsigned short)f2bfbits(softplus_fast(a0));
        unsigned int d1 = (unsigned short)f2bfbits(softplus_fast(a1));
        uint2 o;
        o.x = ((unsigned int)sA[row][e]     << 16) | d0;
        o.y = ((unsigned int)sA[row][e + 1] << 16) | d1;
        *(uint2*)(dxp + (size_t)(row0 + row) * ED_ + e) = o;
    }
}

// ======== chunked selective scan, SEG=32, packed inputs =====================
// Geometric-A fast path (runtime-verified): A_n = (n+1)*A_0 => a_n = r^{n+1}.

__global__ __launch_bounds__(256) void k_scan1(
        const unsigned int* __restrict__ dxp,
        const float* __restrict__ xd,    // B at +16 (row stride 48)
        const float* __restrict__ A_log,
        float2* __restrict__ ph, int layer) {
    __shared__ float s_B[SLEN_][16];
    const int te = threadIdx.x;
    const int bi = blockIdx.x;
    const int seg = bi & (SEG_ - 1);
    const int eh  = (bi >> 5) & 1;
    const int b   = bi >> 6;
    const int e   = eh * 256 + te;
    const int rowbase = b * L_ + seg * SLEN_;

    if (te < SLEN_ * 4) {   // stage B rows: 32 x 16 floats (128 threads)
        int flat = te * 4;
        int r = flat >> 4, c = flat & 15;
        *(float4*)&s_B[r][c] = *(const float4*)(xd + (size_t)(rowbase + r) * 48 + 16 + c);
    }

    float A[16];
    bool geo = true;
    {
        const float* ap = A_log + ((size_t)layer * ED_ + e) * NS_;
        #pragma unroll
        for (int n = 0; n < 16; n++) A[n] = -__expf(ap[n]);
        #pragma unroll
        for (int n = 1; n < 16; n++)
            geo = geo && (fabsf(A[n] - (float)(n + 1) * A[0]) <= 1e-3f * (float)(n + 1) * fabsf(A[0]));
    }

    float h[16];
    #pragma unroll
    for (int n = 0; n < 16; n++) h[n] = 0.f;
    float Pr = 1.0f;
    float P[16];
    #pragma unroll
    for (int n = 0; n < 16; n++) P[n] = 1.f;

    const unsigned int* dptr = dxp + (size_t)rowbase * ED_ + e;

    unsigned int dvx[8];
    #pragma unroll
    for (int j = 0; j < 8; j++) dvx[j] = dptr[(size_t)j * ED_];
    __syncthreads();

    for (int sub = 0; sub < SLEN_ / 8; sub++) {
        unsigned int dnx[8];
        if (sub < SLEN_ / 8 - 1) {
            const unsigned int* d2 = dptr + (size_t)(sub + 1) * 8 * ED_;
            #pragma unroll
            for (int j = 0; j < 8; j++) dnx[j] = d2[(size_t)j * ED_];
        }
        if (geo) {
            #pragma unroll
            for (int j = 0; j < 8; j++) {
                int l = sub * 8 + j;
                float dv = pk_lo(dvx[j]), xv = pk_hi(dvx[j]);
                float dx = dv * xv;
                float Bv[16];
                #pragma unroll
                for (int q = 0; q < 4; q++)
                    *(float4*)&Bv[q * 4] = *(const float4*)&s_B[l][q * 4];
                float r = __expf(dv * A[0]);
                float r2 = r * r, r4 = r2 * r2;
                float a0 = r, a1 = r2, a2 = r2 * r, a3 = r4;
                #pragma unroll
                for (int q = 0; q < 4; q++) {
                    h[4*q+0] = fmaf(a0, h[4*q+0], dx * Bv[4*q+0]);
                    h[4*q+1] = fmaf(a1, h[4*q+1], dx * Bv[4*q+1]);
                    h[4*q+2] = fmaf(a2, h[4*q+2], dx * Bv[4*q+2]);
                    h[4*q+3] = fmaf(a3, h[4*q+3], dx * Bv[4*q+3]);
                    if (q < 3) { a0 *= r4; a1 *= r4; a2 *= r4; a3 *= r4; }
                }
                Pr *= r;
            }
        } else {
            #pragma unroll
            for (int j = 0; j < 8; j++) {
                int l = sub * 8 + j;
                float dv = pk_lo(dvx[j]), xv = pk_hi(dvx[j]);
                float dx = dv * xv;
                float Bv[16];
                #pragma unroll
                for (int q = 0; q < 4; q++)
                    *(float4*)&Bv[q * 4] = *(const float4*)&s_B[l][q * 4];
                #pragma unroll
                for (int n = 0; n < 16; n++) {
                    float a = __expf(dv * A[n]);
                    h[n] = fmaf(a, h[n], dx * Bv[n]);
                    P[n] *= a;
                }
            }
        }
        #pragma unroll
        for (int j = 0; j < 8; j++) dvx[j] = dnx[j];
    }

    if (geo) {
        float p = Pr;
        #pragma unroll
        for (int n = 0; n < 16; n++) { P[n] = p; p *= Pr; }
    }
    #pragma unroll
    for (int n = 0; n < 16; n++) {
        size_t idx = ((((size_t)b * SEG_ + seg) << 4) + n) * ED_ + e;
        ph[idx] = make_float2(P[n], h[n]);
    }
}

// ---------------- cross-segment prefix: hinit[b,s,n,e] = h entering segment s
// 512 blocks x 128 threads (2 blocks/CU): block = (n, eq, b), thread = e-quarter.
__global__ __launch_bounds__(128) void k_hinit(
        const float2* __restrict__ ph,
        float* __restrict__ hinit) {
    const int te = threadIdx.x;         // 0..127
    const int bi = blockIdx.x;          // 512 blocks: n | eq | b
    const int n  = bi & 15;
    const int eq = (bi >> 4) & 3;
    const int b  = bi >> 6;
    const int e  = eq * 128 + te;
    float h = 0.f;
    for (int s = 0; s < SEG_; s++) {
        size_t idx = ((((size_t)b * SEG_ + s) << 4) + n) * ED_ + e;
        hinit[idx] = h;
        float2 v = ph[idx];
        h = fmaf(v.x, h, v.y);
    }
}

// ---------------- FUSED scan3 + K-split out-projection.
// Block = (b, seg, eh): 512 blocks (2 blocks/CU), 256 threads. Scan -> y
// half-tile (32 x 256) into LDS -> 32x256 output tile over this K-half ->
// atomicAdd partials into fp32 x (2 blocks/element; fp32 reorder noise ~1e-7).
__global__ __launch_bounds__(256) void k_scan3_outx(
        const unsigned int* __restrict__ dxp,
        const float* __restrict__ xd,    // B at +16, C at +32 (row stride 48)
        const bf16_t* __restrict__ xz,   // silu(z) at +ED
        const float* __restrict__ A_log, const float* __restrict__ Dp,
        const float* __restrict__ hinit,
        const bf16_t* __restrict__ Bt,   // out_wT for this layer: [256][512]
        float* __restrict__ x, int layer) {
    __shared__ float s_BC[SLEN_][32];
    __shared__ __align__(16) unsigned short sy[SLEN_][264];
    const int te = threadIdx.x;
    const int bi = blockIdx.x;
    const int seg = bi & (SEG_ - 1);
    const int eh  = (bi >> 5) & 1;
    const int b   = bi >> 6;
    const int e   = eh * 256 + te;
    const int rowbase = b * L_ + seg * SLEN_;

    {   // stage B|C rows: 32 x 32 floats, one float4 per thread
        int flat = te * 4;
        int r = flat >> 5, c = flat & 31;
        *(float4*)&s_BC[r][c] = *(const float4*)(xd + (size_t)(rowbase + r) * 48 + 16 + c);
    }

    float A[16];
    bool geo = true;
    {
        const float* ap = A_log + ((size_t)layer * ED_ + e) * NS_;
        #pragma unroll
        for (int n = 0; n < 16; n++) A[n] = -__expf(ap[n]);
        #pragma unroll
        for (int n = 1; n < 16; n++)
            geo = geo && (fabsf(A[n] - (float)(n + 1) * A[0]) <= 1e-3f * (float)(n + 1) * fabsf(A[0]));
    }
    const float D = Dp[layer * ED_ + e];

    float h[16];
    {
        const size_t hb = (((size_t)b * SEG_ + seg) << 4) * ED_ + e;
        #pragma unroll
        for (int n = 0; n < 16; n++) h[n] = hinit[hb + (size_t)n * ED_];
    }

    const unsigned int* dptr = dxp + (size_t)rowbase * ED_ + e;
    const bf16_t* zptr = xz + (size_t)rowbase * (2 * ED_) + ED_ + e;

    unsigned int dvx[8];
    bf16_t zvb[8];
    #pragma unroll
    for (int j = 0; j < 8; j++) {
        dvx[j] = dptr[(size_t)j * ED_];
        zvb[j] = zptr[(size_t)j * (2 * ED_)];
    }
    __syncthreads();

    for (int sub = 0; sub < SLEN_ / 8; sub++) {
        unsigned int dnx[8];
        bf16_t znx[8];
        if (sub < SLEN_ / 8 - 1) {
            const unsigned int* d2 = dptr + (size_t)(sub + 1) * 8 * ED_;
            const bf16_t* z2 = zptr + (size_t)(sub + 1) * 8 * (2 * ED_);
            #pragma unroll
            for (int j = 0; j < 8; j++) {
                dnx[j] = d2[(size_t)j * ED_];
                znx[j] = z2[(size_t)j * (2 * ED_)];
            }
        }
        if (geo) {
            #pragma unroll
            for (int j = 0; j < 8; j++) {
                int l = sub * 8 + j;
                float dv = pk_lo(dvx[j]), xv = pk_hi(dvx[j]);
                float dx = dv * xv;
                float Bv[16], Cv[16];
                #pragma unroll
                for (int q = 0; q < 4; q++) {
                    *(float4*)&Bv[q * 4] = *(const float4*)&s_BC[l][q * 4];
                    *(float4*)&Cv[q * 4] = *(const float4*)&s_BC[l][16 + q * 4];
                }
                float r = __expf(dv * A[0]);
                float r2 = r * r, r4 = r2 * r2;
                float a0 = r, a1 = r2, a2 = r2 * r, a3 = r4;
                float y0 = D * xv, y1 = 0.f, y2 = 0.f, y3 = 0.f;
                #pragma unroll
                for (int q = 0; q < 4; q++) {
                    h[4*q+0] = fmaf(a0, h[4*q+0], dx * Bv[4*q+0]);
                    h[4*q+1] = fmaf(a1, h[4*q+1], dx * Bv[4*q+1]);
                    h[4*q+2] = fmaf(a2, h[4*q+2], dx * Bv[4*q+2]);
                    h[4*q+3] = fmaf(a3, h[4*q+3], dx * Bv[4*q+3]);
                    y0 = fmaf(Cv[4*q+0], h[4*q+0], y0);
                    y1 = fmaf(Cv[4*q+1], h[4*q+1], y1);
                    y2 = fmaf(Cv[4*q+2], h[4*q+2], y2);
                    y3 = fmaf(Cv[4*q+3], h[4*q+3], y3);
                    if (q < 3) { a0 *= r4; a1 *= r4; a2 *= r4; a3 *= r4; }
                }
                float yv = (y0 + y1) + (y2 + y3);
                sy[l][te] = (unsigned short)f2bfbits(yv * b2f(zvb[j]));
            }
        } else {
            #pragma unroll
            for (int j = 0; j < 8; j++) {
                int l = sub * 8 + j;
                float dv = pk_lo(dvx[j]), xv = pk_hi(dvx[j]);
                float dx = dv * xv;
                float Bv[16], Cv[16];
                #pragma unroll
                for (int q = 0; q < 4; q++) {
                    *(float4*)&Bv[q * 4] = *(const float4*)&s_BC[l][q * 4];
                    *(float4*)&Cv[q * 4] = *(const float4*)&s_BC[l][16 + q * 4];
                }
                float y0 = D * xv, y1 = 0.f, y2 = 0.f, y3 = 0.f;
                #pragma unroll
                for (int n = 0; n < 16; n++) {
                    float a = __expf(dv * A[n]);
                    h[n] = fmaf(a, h[n], dx * Bv[n]);
                    float t = Cv[n] * h[n];
                    if ((n & 3) == 0) y0 += t;
                    else if ((n & 3) == 1) y1 += t;
                    else if ((n & 3) == 2) y2 += t;
                    else y3 += t;
                }
                float yv = (y0 + y1) + (y2 + y3);
                sy[l][te] = (unsigned short)f2bfbits(yv * b2f(zvb[j]));
            }
        }
        #pragma unroll
        for (int j = 0; j < 8; j++) { dvx[j] = dnx[j]; zvb[j] = znx[j]; }
    }
    __syncthreads();

    // ---- K-split out-projection: x[32 x 256] += sy(32 x 256) @ Bt[:, Khalf]^T
    {
        const int wave = te >> 6, lane = te & 63;
        const int lrow = lane & 15, lq = lane >> 4;
        const int ct = wave;              // 4 col groups of 64
        floatx4 acc[2][4];
        #pragma unroll
        for (int mt = 0; mt < 2; mt++)
            #pragma unroll
            for (int t = 0; t < 4; t++) acc[mt][t] = (floatx4)0.0f;
        #pragma unroll 2
        for (int kb = 0; kb < 8; kb++) {
            short8 af0 = *(const short8*)&sy[lrow][kb * 32 + lq * 8];
            short8 af1 = *(const short8*)&sy[16 + lrow][kb * 32 + lq * 8];
            #pragma unroll
            for (int t = 0; t < 4; t++) {
                short8 bf = *(const short8*)(
                    Bt + (size_t)(ct * 64 + t * 16 + lrow) * ED_ + eh * 256 + kb * 32 + lq * 8);
                acc[0][t] = __builtin_amdgcn_mfma_f32_16x16x32_bf16(af0, bf, acc[0][t], 0, 0, 0);
                acc[1][t] = __builtin_amdgcn_mfma_f32_16x16x32_bf16(af1, bf, acc[1][t], 0, 0, 0);
            }
        }
        #pragma unroll
        for (int mt = 0; mt < 2; mt++) {
            #pragma unroll
            for (int t = 0; t < 4; t++) {
                int gc = ct * 64 + t * 16 + lrow;
                #pragma unroll
                for (int r = 0; r < 4; r++) {
                    int gr = rowbase + mt * 16 + lq * 4 + r;
                    atomicAdd(&x[(size_t)gr * DM_ + gc], acc[mt][t][r]);
                }
            }
        }
    }
}

// ---------------- final LN + head; wave-per-row, 4 rows/block
__global__ void k_final(const float* __restrict__ x,
                        const float* __restrict__ fg, const float* __restrict__ fb,
                        const float* __restrict__ hw, const float* __restrict__ hb,
                        float* __restrict__ out) {
    int lane = threadIdx.x & 63, w = threadIdx.x >> 6;
    int row = blockIdx.x * 4 + w;
    const float* xr = x + (size_t)row * DM_;
    float v[4];
    #pragma unroll
    for (int k = 0; k < 4; k++) v[k] = xr[lane + 64 * k];
    float s = (v[0] + v[1]) + (v[2] + v[3]);
    float q = (v[0] * v[0] + v[1] * v[1]) + (v[2] * v[2] + v[3] * v[3]);
    #pragma unroll
    for (int off = 32; off > 0; off >>= 1) {
        s += __shfl_xor(s, off, 64);
        q += __shfl_xor(q, off, 64);
    }
    float mean = s * (1.0f / DM_);
    float var = q * (1.0f / DM_) - mean * mean;
    float rstd = rsqrtf(var + 1e-5f);
    float s0 = 0.f, s1 = 0.f;
    #pragma unroll
    for (int k = 0; k < 4; k++) {
        int c = lane + 64 * k;
        float xf = (v[k] - mean) * rstd * fg[c] + fb[c];
        s0 += xf * hw[c * Q_ + 0];
        s1 += xf * hw[c * Q_ + 1];
    }
    #pragma unroll
    for (int off = 32; off > 0; off >>= 1) {
        s0 += __shfl_xor(s0, off, 64);
        s1 += __shfl_xor(s1, off, 64);
    }
    if (lane == 0) {
        out[row * Q_ + 0] = s0 + hb[0];
        out[row * Q_ + 1] = s1 + hb[1];
    }
}

extern "C" void kernel_launch(void* const* d_in, const int* in_sizes, int n_in,
                              void* d_out, int out_size, void* d_ws, size_t ws_size,
                              hipStream_t stream) {
    const int*   tokens    = (const int*)d_in[0];
    const float* T         = (const float*)d_in[1];
    const float* tok_embed = (const float*)d_in[2];
    const float* pos_embed = (const float*)d_in[3];
    const float* tw1       = (const float*)d_in[4];
    const float* tb1       = (const float*)d_in[5];
    const float* tw2       = (const float*)d_in[6];
    const float* tb2       = (const float*)d_in[7];
    const float* ag        = (const float*)d_in[8];
    const float* ab        = (const float*)d_in[9];
    const float* apw       = (const float*)d_in[10];
    const float* apb       = (const float*)d_in[11];
    const float* in_w      = (const float*)d_in[12];
    const float* conv_w    = (const float*)d_in[13];
    const float* conv_b    = (const float*)d_in[14];
    const float* xp_w      = (const float*)d_in[15];
    const float* dt_w      = (const float*)d_in[16];
    const float* dt_b      = (const float*)d_in[17];
    const float* A_log     = (const float*)d_in[18];
    const float* Dp        = (const float*)d_in[19];
    const float* out_w     = (const float*)d_in[20];
    const float* fg        = (const float*)d_in[21];
    const float* fb        = (const float*)d_in[22];
    const float* hw        = (const float*)d_in[23];
    const float* hb        = (const float*)d_in[24];
    float* out = (float*)d_out;

    const int ROWS = B_ * L_;   // 8192

    char* p = (char*)d_ws;
    float*        x      = (float*)p;        p += (size_t)ROWS * DM_ * 4;
    bf16_t*       xn     = (bf16_t*)p;       p += (size_t)ROWS * DM_ * 2;
    bf16_t*       xz     = (bf16_t*)p;       p += (size_t)ROWS * 2 * ED_ * 2;
    unsigned int* dxp    = (unsigned int*)p; p += (size_t)ROWS * ED_ * 4;   // 16 MB
    float*        xd     = (float*)p;        p += (size_t)ROWS * 48 * 4;
    float*        ss     = (float*)p;        p += (size_t)NL_ * B_ * 2 * DM_ * 4;
    float2*       ph     = (float2*)p;       p += (size_t)B_ * SEG_ * NS_ * ED_ * 8;  // 16 MB
    float*        hinit  = (float*)p;        p += (size_t)B_ * SEG_ * NS_ * ED_ * 4;  // 8 MB
    bf16_t*       in_wT  = (bf16_t*)p;       p += (size_t)NL_ * 2 * ED_ * DM_ * 2;
    bf16_t*       xp_wT  = (bf16_t*)p;       p += (size_t)NL_ * 48 * ED_ * 2;
    bf16_t*       out_wT = (bf16_t*)p;       p += (size_t)NL_ * DM_ * ED_ * 2;

    // transpose (z=0..11) + prep (z=12)
    k_transpose_all<<<dim3(32, 16, 13), 256, 0, stream>>>(
        in_w, xp_w, out_w, in_wT, xp_wT, out_wT,
        T, tw1, tb1, tw2, tb2, apw, apb, ss);

    for (int i = 0; i < NL_; i++) {
        if (i == 0) {
            // fused embed + layer-0 LN/adaLN: writes x (residual) and xn
            k_embed_ln_mod<<<ROWS / 4, 256, 0, stream>>>(
                tokens, tok_embed, pos_embed, ag, ab, ss, x, xn);
        } else {
            // xn = mod(LN(x))  (memory-bound, wave/row)
            k_ln_mod<<<ROWS / 4, 256, 0, stream>>>(x, ag, ab, ss, xn, i);
        }
        // xz = xn @ in_w[i]  (128x128 MFMA GEMM, 512 blocks = 2/CU)
        k_gemm_in<<<512, 256, 0, stream>>>(
            xn, in_wT + (size_t)i * 2 * ED_ * DM_, xz);
        // fused conv+silu -> xp GEMM -> packed {xs|dlt} + xd
        k_conv_xp_dlt<<<ROWS / 16, 256, 0, stream>>>(
            xz, conv_w, conv_b, xp_wT + (size_t)i * 48 * ED_, dxp, xd,
            dt_w, dt_b, i);
        // chunked scan (SEG=32 -> 512 blocks, 2 blocks/CU), packed loads
        k_scan1<<<B_ * 2 * SEG_, 256, 0, stream>>>(dxp, xd, A_log, ph, i);
        k_hinit<<<B_ * 4 * NS_, 128, 0, stream>>>(ph, hinit);
        // fused scan3 + K-split out-projection (512 blocks, 2 blocks/CU)
        k_scan3_outx<<<B_ * 2 * SEG_, 256, 0, stream>>>(
            dxp, xd, xz, A_log, Dp, hinit,
            out_wT + (size_t)i * DM_ * ED_, x, i);
    }

    k_final<<<ROWS / 4, 256, 0, stream>>>(x, fg, fb, hw, hb, out);
}

// Round 14
// 418.948 us; speedup vs baseline: 1.0662x; 1.0662x over previous
//
#include <hip/hip_runtime.h>
#include <hip/hip_bf16.h>
#include <math.h>

#define B_   8
#define L_   1024
#define DM_  256
#define NL_  4
#define ED_  512
#define NS_  16
#define DC_  4
#define RK_  16
#define CD_  64
#define Q_   2

#define SEG_  32    // segments along L
#define SLEN_ 32    // L_/SEG_

typedef __hip_bfloat16 bf16_t;
typedef __attribute__((ext_vector_type(8))) short short8;
typedef __attribute__((ext_vector_type(4))) float floatx4;

__device__ __forceinline__ float geluf(float x) {
    return 0.5f * x * (1.0f + erff(x * 0.70710678118654752f));
}
__device__ __forceinline__ float siluf(float x) {
    return x / (1.0f + __expf(-x));
}
// fast softplus: dlt is stored as bf16 (8-bit mantissa) -> ~1e-6 abs error invisible
__device__ __forceinline__ float softplus_fast(float x) {
    return (x > 20.0f) ? x : __logf(1.0f + __expf(x));
}
__device__ __forceinline__ float b2f(bf16_t v) { return __bfloat162float(v); }
__device__ __forceinline__ short f2bfbits(float v) {
    return __builtin_bit_cast(short, __float2bfloat16(v));
}
// packed {xs(hi16) | dlt(lo16)} helpers — bit-identical to separate bf16 loads
__device__ __forceinline__ float pk_lo(unsigned int u) {
    return __uint_as_float(u << 16);
}
__device__ __forceinline__ float pk_hi(unsigned int u) {
    return __uint_as_float(u & 0xFFFF0000u);
}

// ---------------- one-shot batched weight transpose + bf16 convert
__global__ void k_transpose_all(const float* __restrict__ in_w,
                                const float* __restrict__ xp_w,
                                const float* __restrict__ out_w,
                                bf16_t* __restrict__ in_wT,
                                bf16_t* __restrict__ xp_wT,
                                bf16_t* __restrict__ out_wT) {
    __shared__ float t[32][33];
    int z = blockIdx.z;
    int which = z >> 2, layer = z & 3;
    const float* src; bf16_t* dst; int R, C;
    if (which == 0)      { R = DM_; C = 2 * ED_; src = in_w;  dst = in_wT;  }
    else if (which == 1) { R = ED_; C = 48;      src = xp_w;  dst = xp_wT;  }
    else                 { R = ED_; C = DM_;     src = out_w; dst = out_wT; }
    src += (size_t)layer * R * C;
    dst += (size_t)layer * R * C;
    int c0 = blockIdx.x * 32, r0 = blockIdx.y * 32;
    if (c0 >= C || r0 >= R) return;
    int tx = threadIdx.x & 31, ty = threadIdx.x >> 5;   // 32 x 8
    #pragma unroll
    for (int i = 0; i < 32; i += 8) {
        int r = r0 + ty + i, c = c0 + tx;
        t[ty + i][tx] = (r < R && c < C) ? src[(size_t)r * C + c] : 0.f;
    }
    __syncthreads();
    #pragma unroll
    for (int i = 0; i < 32; i += 8) {
        int c = c0 + ty + i, r = r0 + tx;
        if (c < C && r < R) dst[(size_t)c * R + r] = __float2bfloat16(t[tx][ty + i]);
    }
}

// ---------------- conditioning + all-layer adaLN params in one launch
__global__ void k_prep(const float* __restrict__ T,
                       const float* __restrict__ tw1, const float* __restrict__ tb1,
                       const float* __restrict__ tw2, const float* __restrict__ tb2,
                       const float* __restrict__ apw, const float* __restrict__ apb,
                       float* __restrict__ ss) {
    __shared__ float h[CD_], cnd[CD_];
    int b = blockIdx.x, layer = blockIdx.y;
    int j = threadIdx.x;
    if (j < CD_) h[j] = geluf(T[b] * tw1[j] + tb1[j]);
    __syncthreads();
    if (j < CD_) {
        float acc = tb2[j];
        #pragma unroll
        for (int c = 0; c < CD_; c++) acc += h[c] * tw2[c * CD_ + j];
        cnd[j] = acc;
    }
    __syncthreads();
    const float* w = apw + (size_t)layer * CD_ * 2 * DM_;
    float acc = apb[layer * 2 * DM_ + j];
    #pragma unroll
    for (int c = 0; c < CD_; c++) acc += cnd[c] * w[c * 2 * DM_ + j];
    ss[((size_t)layer * B_ + b) * 2 * DM_ + j] = acc;
}

// ---------------- FUSED embed + layer-0 LN/adaLN modulation.
// Wave per row, 4 rows/block. Writes x (residual base) AND xn (layer-0 input).
__global__ __launch_bounds__(256) void k_embed_ln_mod(
        const int* __restrict__ tokens,
        const float* __restrict__ tok_embed,
        const float* __restrict__ pos_embed,
        const float* __restrict__ ag, const float* __restrict__ ab,
        const float* __restrict__ ss,
        float* __restrict__ x, bf16_t* __restrict__ xn) {
    int lane = threadIdx.x & 63, w = threadIdx.x >> 6;
    int row = blockIdx.x * 4 + w;
    int b = row >> 10, l = row & (L_ - 1);
    int tok = (l > 0) ? tokens[b * L_ + l - 1] : 0;
    float v[4];
    #pragma unroll
    for (int k = 0; k < 4; k++) {
        int c = lane + 64 * k;
        float val = pos_embed[l * DM_ + c];
        if (l > 0) val += tok_embed[tok * DM_ + c];
        v[k] = val;
        x[(size_t)row * DM_ + c] = val;
    }
    float s = (v[0] + v[1]) + (v[2] + v[3]);
    float q = (v[0] * v[0] + v[1] * v[1]) + (v[2] * v[2] + v[3] * v[3]);
    #pragma unroll
    for (int off = 32; off > 0; off >>= 1) {
        s += __shfl_xor(s, off, 64);
        q += __shfl_xor(q, off, 64);
    }
    float mean = s * (1.0f / DM_);
    float var = q * (1.0f / DM_) - mean * mean;
    float rstd = rsqrtf(var + 1e-5f);
    const float* ssl = ss + (size_t)b * 2 * DM_;   // layer 0
    #pragma unroll
    for (int k = 0; k < 4; k++) {
        int c = lane + 64 * k;
        float ln = (v[k] - mean) * rstd * ag[c] + ab[c];
        float val = (1.0f + ssl[c]) * ln + ssl[DM_ + c];
        xn[(size_t)row * DM_ + c] = __float2bfloat16(val);
    }
}

// ---------------- LN + adaLN modulation -> xn (bf16). Wave per row, 4 rows/block.
__global__ __launch_bounds__(256) void k_ln_mod(
        const float* __restrict__ x,
        const float* __restrict__ ag, const float* __restrict__ ab,
        const float* __restrict__ ss,
        bf16_t* __restrict__ xn, int layer) {
    int lane = threadIdx.x & 63, w = threadIdx.x >> 6;
    int row = blockIdx.x * 4 + w;
    int b = row >> 10;            // / L_
    const float* xr = x + (size_t)row * DM_;
    float v[4];
    #pragma unroll
    for (int k = 0; k < 4; k++) v[k] = xr[lane + 64 * k];
    float s = (v[0] + v[1]) + (v[2] + v[3]);
    float q = (v[0] * v[0] + v[1] * v[1]) + (v[2] * v[2] + v[3] * v[3]);
    #pragma unroll
    for (int off = 32; off > 0; off >>= 1) {
        s += __shfl_xor(s, off, 64);
        q += __shfl_xor(q, off, 64);
    }
    float mean = s * (1.0f / DM_);
    float var = q * (1.0f / DM_) - mean * mean;
    float rstd = rsqrtf(var + 1e-5f);
    const float* ssl = ss + ((size_t)layer * B_ + b) * 2 * DM_;
    #pragma unroll
    for (int k = 0; k < 4; k++) {
        int c = lane + 64 * k;
        float ln = (v[k] - mean) * rstd * ag[layer * DM_ + c] + ab[layer * DM_ + c];
        float val = (1.0f + ssl[c]) * ln + ssl[DM_ + c];
        xn[(size_t)row * DM_ + c] = __float2bfloat16(val);
    }
}

// ---------------- in-projection GEMM: xz = xn @ in_wT^T, silu on z half.
// BM=128 x BN=128, 512 blocks (2 blocks/CU), 16 MFMA/wave/K-step.
__global__ __launch_bounds__(256) void k_gemm_in(
        const bf16_t* __restrict__ A, const bf16_t* __restrict__ Bt,
        bf16_t* __restrict__ xz) {
    constexpr int BM = 128, BN = 128, K = 256, N = 2 * ED_;
    constexpr int TM = 4, TN = 4;
    __shared__ __align__(16) unsigned short sA[BM * 40];
    __shared__ __align__(16) unsigned short sB[BN * 40];

    const int tid = threadIdx.x;
    const int wave = tid >> 6, lane = tid & 63;
    const int lrow = lane & 15, lq = lane >> 4;
    const int nrt = (B_ * L_) / BM;     // 64
    const int bi = blockIdx.x;
    const int row0 = (bi % nrt) * BM, col0 = (bi / nrt) * BN;
    const int wm0 = (wave >> 1) * 64;
    const int wn0 = (wave & 1) * 64;

    floatx4 acc[TM][TN];
    #pragma unroll
    for (int i = 0; i < TM; i++)
        #pragma unroll
        for (int j = 0; j < TN; j++) acc[i][j] = (floatx4)0.0f;

    short8 ra[2], rb[2];
    const int NKB = K / 32;   // 8

    #pragma unroll
    for (int i = 0; i < 2; i++) {
        int v = tid + i * 256;          // 0..511, m in 0..127
        int m = v >> 2, ko = (v & 3) * 8;
        ra[i] = *(const short8*)(A + (size_t)(row0 + m) * K + ko);
        rb[i] = *(const short8*)(Bt + (size_t)(col0 + m) * K + ko);
    }

    for (int kb = 0; kb < NKB; kb++) {
        __syncthreads();
        #pragma unroll
        for (int i = 0; i < 2; i++) {
            int v = tid + i * 256;
            int m = v >> 2, ko = (v & 3) * 8;
            *(short8*)&sA[m * 40 + ko] = ra[i];
            *(short8*)&sB[m * 40 + ko] = rb[i];
        }
        __syncthreads();
        if (kb + 1 < NKB) {
            int k0 = (kb + 1) * 32;
            #pragma unroll
            for (int i = 0; i < 2; i++) {
                int v = tid + i * 256;
                int m = v >> 2, ko = (v & 3) * 8;
                ra[i] = *(const short8*)(A + (size_t)(row0 + m) * K + k0 + ko);
                rb[i] = *(const short8*)(Bt + (size_t)(col0 + m) * K + k0 + ko);
            }
        }
        short8 af[TM], bfr[TN];
        #pragma unroll
        for (int i = 0; i < TM; i++)
            af[i] = *(const short8*)&sA[(wm0 + i * 16 + lrow) * 40 + lq * 8];
        #pragma unroll
        for (int j = 0; j < TN; j++)
            bfr[j] = *(const short8*)&sB[(wn0 + j * 16 + lrow) * 40 + lq * 8];
        #pragma unroll
        for (int i = 0; i < TM; i++)
            #pragma unroll
            for (int j = 0; j < TN; j++)
                acc[i][j] = __builtin_amdgcn_mfma_f32_16x16x32_bf16(af[i], bfr[j], acc[i][j], 0, 0, 0);
    }

    #pragma unroll
    for (int i = 0; i < TM; i++) {
        int gr0 = row0 + wm0 + i * 16 + lq * 4;
        #pragma unroll
        for (int j = 0; j < TN; j++) {
            int gc = col0 + wn0 + j * 16 + lrow;
            #pragma unroll
            for (int r = 0; r < 4; r++) {
                float val = acc[i][j][r];
                if (gc >= ED_) val = siluf(val);
                xz[(size_t)(gr0 + r) * N + gc] = __float2bfloat16(val);
            }
        }
    }
}

// ---------------- FUSED: causal depthwise conv(DC=4)+SiLU -> LDS A-tile ->
// xp-projection GEMM (B from L2, barrier-free K-loop) -> packed {xs|dlt}.
// BM=16 -> 512 blocks (2 blocks/CU).
__global__ __launch_bounds__(256) void k_conv_xp_dlt(
        const bf16_t* __restrict__ xz,
        const float* __restrict__ conv_w, const float* __restrict__ conv_b,
        const bf16_t* __restrict__ Bt,      // xp_wT for this layer: [48][512]
        unsigned int* __restrict__ dxp,     // packed {xs(hi)|dlt(lo)} per (row,e)
        float* __restrict__ xd,
        const float* __restrict__ dt_w, const float* __restrict__ dt_b,
        int layer) {
    constexpr int K = ED_;   // 512
    constexpr int BM = 16;
    __shared__ __align__(16) unsigned short sA[BM][520];
    __shared__ __align__(16) float s_rk[BM][20];

    const int tid = threadIdx.x;
    const int wave = tid >> 6, lane = tid & 63;
    const int lrow = lane & 15, lq = lane >> 4;
    const int row0 = blockIdx.x * BM;
    const int b = row0 >> 10;           // / L_
    const int l0 = row0 & (L_ - 1);

    // ---- conv + silu: thread owns columns e0, e0+1 for rows row0..row0+15
    {
        const int e0 = tid * 2;
        float4 w0 = *(const float4*)(conv_w + ((size_t)layer * ED_ + e0) * DC_);
        float4 w1 = *(const float4*)(conv_w + ((size_t)layer * ED_ + e0 + 1) * DC_);
        float bias0 = conv_b[layer * ED_ + e0];
        float bias1 = conv_b[layer * ED_ + e0 + 1];
        const float wa0[4] = {w0.x, w0.y, w0.z, w0.w};
        const float wa1[4] = {w1.x, w1.y, w1.z, w1.w};
        float v0[BM + 3], v1[BM + 3];
        #pragma unroll
        for (int k = 0; k < BM + 3; k++) {
            int ll = l0 - 3 + k;
            if (ll >= 0) {
                __hip_bfloat162 v = *(const __hip_bfloat162*)(
                    xz + ((size_t)(b * L_ + ll)) * (2 * ED_) + e0);
                v0[k] = b2f(v.x); v1[k] = b2f(v.y);
            } else { v0[k] = 0.f; v1[k] = 0.f; }
        }
        #pragma unroll
        for (int j = 0; j < BM; j++) {
            float a0 = bias0, a1 = bias1;
            #pragma unroll
            for (int k = 0; k < DC_; k++) {
                a0 = fmaf(v0[j + k], wa0[k], a0);
                a1 = fmaf(v1[j + k], wa1[k], a1);
            }
            __hip_bfloat162 o;
            o.x = __float2bfloat16(siluf(a0));
            o.y = __float2bfloat16(siluf(a1));
            *(__hip_bfloat162*)&sA[j][e0] = o;     // xs bits live in LDS only
        }
    }
    __syncthreads();

    // ---- GEMM from LDS A + global(L2) B, no barriers in K-loop
    const int nrow = (wave < 3) ? (wave * 16 + lrow) : lrow;  // wave3 clamped
    const bf16_t* bptr = Bt + (size_t)nrow * K + lq * 8;
    floatx4 acc = (floatx4)0.0f;
    #pragma unroll
    for (int kb = 0; kb < K / 32; kb++) {
        short8 af = *(const short8*)&sA[lrow][kb * 32 + lq * 8];
        short8 bf = *(const short8*)(bptr + kb * 32);
        acc = __builtin_amdgcn_mfma_f32_16x16x32_bf16(af, bf, acc, 0, 0, 0);
    }

    if (wave == 1 || wave == 2) {
        int gc = wave * 16 + lrow;
        #pragma unroll
        for (int r = 0; r < 4; r++) {
            int gr = row0 + lq * 4 + r;
            xd[(size_t)gr * 48 + gc] = acc[r];
        }
    }
    if (wave == 0) {
        #pragma unroll
        for (int r = 0; r < 4; r++)
            s_rk[lq * 4 + r][lrow] = acc[r];
    }
    __syncthreads();

    // ---- dlt = softplus(rk @ dt_w + dt_b); pack with xs bits -> dxp
    const int e = 2 * tid;
    float2 wv[16];
    #pragma unroll
    for (int r = 0; r < RK_; r++)
        wv[r] = *(const float2*)(dt_w + ((size_t)layer * RK_ + r) * ED_ + e);
    float2 bb = *(const float2*)(dt_b + (size_t)layer * ED_ + e);
    #pragma unroll 4
    for (int row = 0; row < BM; row++) {
        float rk[16];
        #pragma unroll
        for (int q = 0; q < 4; q++)
            *(float4*)&rk[q * 4] = *(const float4*)&s_rk[row][q * 4];
        float a0 = bb.x, a1 = bb.y;
        #pragma unroll
        for (int r = 0; r < RK_; r++) {
            a0 = fmaf(rk[r], wv[r].x, a0);
            a1 = fmaf(rk[r], wv[r].y, a1);
        }
        unsigned int d0 = (unsigned short)f2bfbits(softplus_fast(a0));
        unsigned int d1 = (unsigned short)f2bfbits(softplus_fast(a1));
        uint2 o;
        o.x = ((unsigned int)sA[row][e]     << 16) | d0;
        o.y = ((unsigned int)sA[row][e + 1] << 16) | d1;
        *(uint2*)(dxp + (size_t)(row0 + row) * ED_ + e) = o;
    }
}

// ======== chunked selective scan, SEG=32, packed inputs =====================
// Geometric-A fast path (runtime-verified): A_n = (n+1)*A_0 => a_n = r^{n+1}.

__global__ __launch_bounds__(256) void k_scan1(
        const unsigned int* __restrict__ dxp,
        const float* __restrict__ xd,    // B at +16 (row stride 48)
        const float* __restrict__ A_log,
        float2* __restrict__ ph, int layer) {
    __shared__ float s_B[SLEN_][16];
    const int te = threadIdx.x;
    const int bi = blockIdx.x;
    const int seg = bi & (SEG_ - 1);
    const int eh  = (bi >> 5) & 1;
    const int b   = bi >> 6;
    const int e   = eh * 256 + te;
    const int rowbase = b * L_ + seg * SLEN_;

    if (te < SLEN_ * 4) {   // stage B rows: 32 x 16 floats (128 threads)
        int flat = te * 4;
        int r = flat >> 4, c = flat & 15;
        *(float4*)&s_B[r][c] = *(const float4*)(xd + (size_t)(rowbase + r) * 48 + 16 + c);
    }

    float A[16];
    bool geo = true;
    {
        const float* ap = A_log + ((size_t)layer * ED_ + e) * NS_;
        #pragma unroll
        for (int n = 0; n < 16; n++) A[n] = -__expf(ap[n]);
        #pragma unroll
        for (int n = 1; n < 16; n++)
            geo = geo && (fabsf(A[n] - (float)(n + 1) * A[0]) <= 1e-3f * (float)(n + 1) * fabsf(A[0]));
    }

    float h[16];
    #pragma unroll
    for (int n = 0; n < 16; n++) h[n] = 0.f;
    float Pr = 1.0f;
    float P[16];
    #pragma unroll
    for (int n = 0; n < 16; n++) P[n] = 1.f;

    const unsigned int* dptr = dxp + (size_t)rowbase * ED_ + e;

    unsigned int dvx[8];
    #pragma unroll
    for (int j = 0; j < 8; j++) dvx[j] = dptr[(size_t)j * ED_];
    __syncthreads();

    for (int sub = 0; sub < SLEN_ / 8; sub++) {
        unsigned int dnx[8];
        if (sub < SLEN_ / 8 - 1) {
            const unsigned int* d2 = dptr + (size_t)(sub + 1) * 8 * ED_;
            #pragma unroll
            for (int j = 0; j < 8; j++) dnx[j] = d2[(size_t)j * ED_];
        }
        if (geo) {
            #pragma unroll
            for (int j = 0; j < 8; j++) {
                int l = sub * 8 + j;
                float dv = pk_lo(dvx[j]), xv = pk_hi(dvx[j]);
                float dx = dv * xv;
                float Bv[16];
                #pragma unroll
                for (int q = 0; q < 4; q++)
                    *(float4*)&Bv[q * 4] = *(const float4*)&s_B[l][q * 4];
                float r = __expf(dv * A[0]);
                float r2 = r * r, r4 = r2 * r2;
                float a0 = r, a1 = r2, a2 = r2 * r, a3 = r4;
                #pragma unroll
                for (int q = 0; q < 4; q++) {
                    h[4*q+0] = fmaf(a0, h[4*q+0], dx * Bv[4*q+0]);
                    h[4*q+1] = fmaf(a1, h[4*q+1], dx * Bv[4*q+1]);
                    h[4*q+2] = fmaf(a2, h[4*q+2], dx * Bv[4*q+2]);
                    h[4*q+3] = fmaf(a3, h[4*q+3], dx * Bv[4*q+3]);
                    if (q < 3) { a0 *= r4; a1 *= r4; a2 *= r4; a3 *= r4; }
                }
                Pr *= r;
            }
        } else {
            #pragma unroll
            for (int j = 0; j < 8; j++) {
                int l = sub * 8 + j;
                float dv = pk_lo(dvx[j]), xv = pk_hi(dvx[j]);
                float dx = dv * xv;
                float Bv[16];
                #pragma unroll
                for (int q = 0; q < 4; q++)
                    *(float4*)&Bv[q * 4] = *(const float4*)&s_B[l][q * 4];
                #pragma unroll
                for (int n = 0; n < 16; n++) {
                    float a = __expf(dv * A[n]);
                    h[n] = fmaf(a, h[n], dx * Bv[n]);
                    P[n] *= a;
                }
            }
        }
        #pragma unroll
        for (int j = 0; j < 8; j++) dvx[j] = dnx[j];
    }

    if (geo) {
        float p = Pr;
        #pragma unroll
        for (int n = 0; n < 16; n++) { P[n] = p; p *= Pr; }
    }
    #pragma unroll
    for (int n = 0; n < 16; n++) {
        size_t idx = ((((size_t)b * SEG_ + seg) << 4) + n) * ED_ + e;
        ph[idx] = make_float2(P[n], h[n]);
    }
}

// ---------------- cross-segment prefix: hinit[b,s,n,e] = h entering segment s
// 512 blocks x 128 threads (2 blocks/CU): block = (n, eq, b), thread = e-quarter.
__global__ __launch_bounds__(128) void k_hinit(
        const float2* __restrict__ ph,
        float* __restrict__ hinit) {
    const int te = threadIdx.x;         // 0..127
    const int bi = blockIdx.x;          // 512 blocks: n | eq | b
    const int n  = bi & 15;
    const int eq = (bi >> 4) & 3;
    const int b  = bi >> 6;
    const int e  = eq * 128 + te;
    float h = 0.f;
    for (int s = 0; s < SEG_; s++) {
        size_t idx = ((((size_t)b * SEG_ + s) << 4) + n) * ED_ + e;
        hinit[idx] = h;
        float2 v = ph[idx];
        h = fmaf(v.x, h, v.y);
    }
}

// ---------------- FUSED scan3 + K-split out-projection.
// Block = (b, seg, eh): 512 blocks (2 blocks/CU), 256 threads. Scan -> y
// half-tile (32 x 256) into LDS -> 32x256 output tile over this K-half ->
// atomicAdd partials into fp32 x (2 blocks/element; fp32 reorder noise ~1e-7).
__global__ __launch_bounds__(256) void k_scan3_outx(
        const unsigned int* __restrict__ dxp,
        const float* __restrict__ xd,    // B at +16, C at +32 (row stride 48)
        const bf16_t* __restrict__ xz,   // silu(z) at +ED
        const float* __restrict__ A_log, const float* __restrict__ Dp,
        const float* __restrict__ hinit,
        const bf16_t* __restrict__ Bt,   // out_wT for this layer: [256][512]
        float* __restrict__ x, int layer) {
    __shared__ float s_BC[SLEN_][32];
    __shared__ __align__(16) unsigned short sy[SLEN_][264];
    const int te = threadIdx.x;
    const int bi = blockIdx.x;
    const int seg = bi & (SEG_ - 1);
    const int eh  = (bi >> 5) & 1;
    const int b   = bi >> 6;
    const int e   = eh * 256 + te;
    const int rowbase = b * L_ + seg * SLEN_;

    {   // stage B|C rows: 32 x 32 floats, one float4 per thread
        int flat = te * 4;
        int r = flat >> 5, c = flat & 31;
        *(float4*)&s_BC[r][c] = *(const float4*)(xd + (size_t)(rowbase + r) * 48 + 16 + c);
    }

    float A[16];
    bool geo = true;
    {
        const float* ap = A_log + ((size_t)layer * ED_ + e) * NS_;
        #pragma unroll
        for (int n = 0; n < 16; n++) A[n] = -__expf(ap[n]);
        #pragma unroll
        for (int n = 1; n < 16; n++)
            geo = geo && (fabsf(A[n] - (float)(n + 1) * A[0]) <= 1e-3f * (float)(n + 1) * fabsf(A[0]));
    }
    const float D = Dp[layer * ED_ + e];

    float h[16];
    {
        const size_t hb = (((size_t)b * SEG_ + seg) << 4) * ED_ + e;
        #pragma unroll
        for (int n = 0; n < 16; n++) h[n] = hinit[hb + (size_t)n * ED_];
    }

    const unsigned int* dptr = dxp + (size_t)rowbase * ED_ + e;
    const bf16_t* zptr = xz + (size_t)rowbase * (2 * ED_) + ED_ + e;

    unsigned int dvx[8];
    bf16_t zvb[8];
    #pragma unroll
    for (int j = 0; j < 8; j++) {
        dvx[j] = dptr[(size_t)j * ED_];
        zvb[j] = zptr[(size_t)j * (2 * ED_)];
    }
    __syncthreads();

    for (int sub = 0; sub < SLEN_ / 8; sub++) {
        unsigned int dnx[8];
        bf16_t znx[8];
        if (sub < SLEN_ / 8 - 1) {
            const unsigned int* d2 = dptr + (size_t)(sub + 1) * 8 * ED_;
            const bf16_t* z2 = zptr + (size_t)(sub + 1) * 8 * (2 * ED_);
            #pragma unroll
            for (int j = 0; j < 8; j++) {
                dnx[j] = d2[(size_t)j * ED_];
                znx[j] = z2[(size_t)j * (2 * ED_)];
            }
        }
        if (geo) {
            #pragma unroll
            for (int j = 0; j < 8; j++) {
                int l = sub * 8 + j;
                float dv = pk_lo(dvx[j]), xv = pk_hi(dvx[j]);
                float dx = dv * xv;
                float Bv[16], Cv[16];
                #pragma unroll
                for (int q = 0; q < 4; q++) {
                    *(float4*)&Bv[q * 4] = *(const float4*)&s_BC[l][q * 4];
                    *(float4*)&Cv[q * 4] = *(const float4*)&s_BC[l][16 + q * 4];
                }
                float r = __expf(dv * A[0]);
                float r2 = r * r, r4 = r2 * r2;
                float a0 = r, a1 = r2, a2 = r2 * r, a3 = r4;
                float y0 = D * xv, y1 = 0.f, y2 = 0.f, y3 = 0.f;
                #pragma unroll
                for (int q = 0; q < 4; q++) {
                    h[4*q+0] = fmaf(a0, h[4*q+0], dx * Bv[4*q+0]);
                    h[4*q+1] = fmaf(a1, h[4*q+1], dx * Bv[4*q+1]);
                    h[4*q+2] = fmaf(a2, h[4*q+2], dx * Bv[4*q+2]);
                    h[4*q+3] = fmaf(a3, h[4*q+3], dx * Bv[4*q+3]);
                    y0 = fmaf(Cv[4*q+0], h[4*q+0], y0);
                    y1 = fmaf(Cv[4*q+1], h[4*q+1], y1);
                    y2 = fmaf(Cv[4*q+2], h[4*q+2], y2);
                    y3 = fmaf(Cv[4*q+3], h[4*q+3], y3);
                    if (q < 3) { a0 *= r4; a1 *= r4; a2 *= r4; a3 *= r4; }
                }
                float yv = (y0 + y1) + (y2 + y3);
                sy[l][te] = (unsigned short)f2bfbits(yv * b2f(zvb[j]));
            }
        } else {
            #pragma unroll
            for (int j = 0; j < 8; j++) {
                int l = sub * 8 + j;
                float dv = pk_lo(dvx[j]), xv = pk_hi(dvx[j]);
                float dx = dv * xv;
                float Bv[16], Cv[16];
                #pragma unroll
                for (int q = 0; q < 4; q++) {
                    *(float4*)&Bv[q * 4] = *(const float4*)&s_BC[l][q * 4];
                    *(float4*)&Cv[q * 4] = *(const float4*)&s_BC[l][16 + q * 4];
                }
                float y0 = D * xv, y1 = 0.f, y2 = 0.f, y3 = 0.f;
                #pragma unroll
                for (int n = 0; n < 16; n++) {
                    float a = __expf(dv * A[n]);
                    h[n] = fmaf(a, h[n], dx * Bv[n]);
                    float t = Cv[n] * h[n];
                    if ((n & 3) == 0) y0 += t;
                    else if ((n & 3) == 1) y1 += t;
                    else if ((n & 3) == 2) y2 += t;
                    else y3 += t;
                }
                float yv = (y0 + y1) + (y2 + y3);
                sy[l][te] = (unsigned short)f2bfbits(yv * b2f(zvb[j]));
            }
        }
        #pragma unroll
        for (int j = 0; j < 8; j++) { dvx[j] = dnx[j]; zvb[j] = znx[j]; }
    }
    __syncthreads();

    // ---- K-split out-projection: x[32 x 256] += sy(32 x 256) @ Bt[:, Khalf]^T
    {
        const int wave = te >> 6, lane = te & 63;
        const int lrow = lane & 15, lq = lane >> 4;
        const int ct = wave;              // 4 col groups of 64
        floatx4 acc[2][4];
        #pragma unroll
        for (int mt = 0; mt < 2; mt++)
            #pragma unroll
            for (int t = 0; t < 4; t++) acc[mt][t] = (floatx4)0.0f;
        #pragma unroll 2
        for (int kb = 0; kb < 8; kb++) {
            short8 af0 = *(const short8*)&sy[lrow][kb * 32 + lq * 8];
            short8 af1 = *(const short8*)&sy[16 + lrow][kb * 32 + lq * 8];
            #pragma unroll
            for (int t = 0; t < 4; t++) {
                short8 bf = *(const short8*)(
                    Bt + (size_t)(ct * 64 + t * 16 + lrow) * ED_ + eh * 256 + kb * 32 + lq * 8);
                acc[0][t] = __builtin_amdgcn_mfma_f32_16x16x32_bf16(af0, bf, acc[0][t], 0, 0, 0);
                acc[1][t] = __builtin_amdgcn_mfma_f32_16x16x32_bf16(af1, bf, acc[1][t], 0, 0, 0);
            }
        }
        #pragma unroll
        for (int mt = 0; mt < 2; mt++) {
            #pragma unroll
            for (int t = 0; t < 4; t++) {
                int gc = ct * 64 + t * 16 + lrow;
                #pragma unroll
                for (int r = 0; r < 4; r++) {
                    int gr = rowbase + mt * 16 + lq * 4 + r;
                    atomicAdd(&x[(size_t)gr * DM_ + gc], acc[mt][t][r]);
                }
            }
        }
    }
}

// ---------------- final LN + head; wave-per-row, 4 rows/block
__global__ void k_final(const float* __restrict__ x,
                        const float* __restrict__ fg, const float* __restrict__ fb,
                        const float* __restrict__ hw, const float* __restrict__ hb,
                        float* __restrict__ out) {
    int lane = threadIdx.x & 63, w = threadIdx.x >> 6;
    int row = blockIdx.x * 4 + w;
    const float* xr = x + (size_t)row * DM_;
    float v[4];
    #pragma unroll
    for (int k = 0; k < 4; k++) v[k] = xr[lane + 64 * k];
    float s = (v[0] + v[1]) + (v[2] + v[3]);
    float q = (v[0] * v[0] + v[1] * v[1]) + (v[2] * v[2] + v[3] * v[3]);
    #pragma unroll
    for (int off = 32; off > 0; off >>= 1) {
        s += __shfl_xor(s, off, 64);
        q += __shfl_xor(q, off, 64);
    }
    float mean = s * (1.0f / DM_);
    float var = q * (1.0f / DM_) - mean * mean;
    float rstd = rsqrtf(var + 1e-5f);
    float s0 = 0.f, s1 = 0.f;
    #pragma unroll
    for (int k = 0; k < 4; k++) {
        int c = lane + 64 * k;
        float xf = (v[k] - mean) * rstd * fg[c] + fb[c];
        s0 += xf * hw[c * Q_ + 0];
        s1 += xf * hw[c * Q_ + 1];
    }
    #pragma unroll
    for (int off = 32; off > 0; off >>= 1) {
        s0 += __shfl_xor(s0, off, 64);
        s1 += __shfl_xor(s1, off, 64);
    }
    if (lane == 0) {
        out[row * Q_ + 0] = s0 + hb[0];
        out[row * Q_ + 1] = s1 + hb[1];
    }
}

extern "C" void kernel_launch(void* const* d_in, const int* in_sizes, int n_in,
                              void* d_out, int out_size, void* d_ws, size_t ws_size,
                              hipStream_t stream) {
    const int*   tokens    = (const int*)d_in[0];
    const float* T         = (const float*)d_in[1];
    const float* tok_embed = (const float*)d_in[2];
    const float* pos_embed = (const float*)d_in[3];
    const float* tw1       = (const float*)d_in[4];
    const float* tb1       = (const float*)d_in[5];
    const float* tw2       = (const float*)d_in[6];
    const float* tb2       = (const float*)d_in[7];
    const float* ag        = (const float*)d_in[8];
    const float* ab        = (const float*)d_in[9];
    const float* apw       = (const float*)d_in[10];
    const float* apb       = (const float*)d_in[11];
    const float* in_w      = (const float*)d_in[12];
    const float* conv_w    = (const float*)d_in[13];
    const float* conv_b    = (const float*)d_in[14];
    const float* xp_w      = (const float*)d_in[15];
    const float* dt_w      = (const float*)d_in[16];
    const float* dt_b      = (const float*)d_in[17];
    const float* A_log     = (const float*)d_in[18];
    const float* Dp        = (const float*)d_in[19];
    const float* out_w     = (const float*)d_in[20];
    const float* fg        = (const float*)d_in[21];
    const float* fb        = (const float*)d_in[22];
    const float* hw        = (const float*)d_in[23];
    const float* hb        = (const float*)d_in[24];
    float* out = (float*)d_out;

    const int ROWS = B_ * L_;   // 8192

    char* p = (char*)d_ws;
    float*        x      = (float*)p;        p += (size_t)ROWS * DM_ * 4;
    bf16_t*       xn     = (bf16_t*)p;       p += (size_t)ROWS * DM_ * 2;
    bf16_t*       xz     = (bf16_t*)p;       p += (size_t)ROWS * 2 * ED_ * 2;
    unsigned int* dxp    = (unsigned int*)p; p += (size_t)ROWS * ED_ * 4;   // 16 MB
    float*        xd     = (float*)p;        p += (size_t)ROWS * 48 * 4;
    float*        ss     = (float*)p;        p += (size_t)NL_ * B_ * 2 * DM_ * 4;
    float2*       ph     = (float2*)p;       p += (size_t)B_ * SEG_ * NS_ * ED_ * 8;  // 16 MB
    float*        hinit  = (float*)p;        p += (size_t)B_ * SEG_ * NS_ * ED_ * 4;  // 8 MB
    bf16_t*       in_wT  = (bf16_t*)p;       p += (size_t)NL_ * 2 * ED_ * DM_ * 2;
    bf16_t*       xp_wT  = (bf16_t*)p;       p += (size_t)NL_ * 48 * ED_ * 2;
    bf16_t*       out_wT = (bf16_t*)p;       p += (size_t)NL_ * DM_ * ED_ * 2;

    k_transpose_all<<<dim3(32, 16, 12), 256, 0, stream>>>(
        in_w, xp_w, out_w, in_wT, xp_wT, out_wT);
    k_prep<<<dim3(B_, NL_), 2 * DM_, 0, stream>>>(T, tw1, tb1, tw2, tb2, apw, apb, ss);

    for (int i = 0; i < NL_; i++) {
        if (i == 0) {
            // fused embed + layer-0 LN/adaLN: writes x (residual) and xn
            k_embed_ln_mod<<<ROWS / 4, 256, 0, stream>>>(
                tokens, tok_embed, pos_embed, ag, ab, ss, x, xn);
        } else {
            // xn = mod(LN(x))  (memory-bound, wave/row)
            k_ln_mod<<<ROWS / 4, 256, 0, stream>>>(x, ag, ab, ss, xn, i);
        }
        // xz = xn @ in_w[i]  (128x128 MFMA GEMM, 512 blocks = 2/CU)
        k_gemm_in<<<512, 256, 0, stream>>>(
            xn, in_wT + (size_t)i * 2 * ED_ * DM_, xz);
        // fused conv+silu -> xp GEMM -> packed {xs|dlt} + xd
        k_conv_xp_dlt<<<ROWS / 16, 256, 0, stream>>>(
            xz, conv_w, conv_b, xp_wT + (size_t)i * 48 * ED_, dxp, xd,
            dt_w, dt_b, i);
        // chunked scan (SEG=32 -> 512 blocks, 2 blocks/CU), packed loads
        k_scan1<<<B_ * 2 * SEG_, 256, 0, stream>>>(dxp, xd, A_log, ph, i);
        k_hinit<<<B_ * 4 * NS_, 128, 0, stream>>>(ph, hinit);
        // fused scan3 + K-split out-projection (512 blocks, 2 blocks/CU)
        k_scan3_outx<<<B_ * 2 * SEG_, 256, 0, stream>>>(
            dxp, xd, xz, A_log, Dp, hinit,
            out_wT + (size_t)i * DM_ * ED_, x, i);
    }

    k_final<<<ROWS / 4, 256, 0, stream>>>(x, fg, fb, hw, hb, out);
}